// Round 4
// baseline (239.005 us; speedup 1.0000x reference)
//
#include <hip/hip_runtime.h>

#define NPIX 9216
#define CIN 72
#define CP 96
#define SPLITS 16
#define JCHUNK (NPIX / SPLITS)   // 576
#define JTILES (JCHUNK / 64)     // 9
// p = exp2(s*log2e - 32*log2e)  (fixed softmax shift 32; safe to s<120)
#define L2E   1.44269504088896f
#define EXPB  46.1662413084468f

typedef __attribute__((ext_vector_type(8))) short bf16x8;
typedef __attribute__((ext_vector_type(8))) _Float16 f16x8;
typedef __attribute__((ext_vector_type(4))) float f32x4;

#define MFMA_BF16(A,B,C) __builtin_amdgcn_mfma_f32_16x16x32_bf16(A,B,C,0,0,0)
#define MFMA_F16(A,B,C)  __builtin_amdgcn_mfma_f32_16x16x32_f16(A,B,C,0,0,0)

static __device__ __forceinline__ unsigned short f2bf(float f) {
  unsigned u = __float_as_uint(f);
  u += 0x7fffu + ((u >> 16) & 1u);
  return (unsigned short)(u >> 16);
}
static __device__ __forceinline__ float bf2f(unsigned short h) {
  return __uint_as_float(((unsigned)h) << 16);
}
static __device__ __forceinline__ unsigned short f2h(float f) {
  _Float16 h = (_Float16)f;
  return *(unsigned short*)&h;
}
// pack trunc-bf16 of (lo,hi) into one dword: [lo.hi16 | hi.hi16]
static __device__ __forceinline__ unsigned pack_bf_trunc(float lo, float hi) {
  return (__float_as_uint(lo) >> 16) | (__float_as_uint(hi) & 0xffff0000u);
}
// async global->LDS DMA, 16B per lane; lds dest = uniform base + lane*16.
// global src is PER-LANE (m173): fragment-order LDS = per-lane gather src.
static __device__ __forceinline__ void load_lds16(const void* g, void* l) {
  __builtin_amdgcn_global_load_lds(
      (const __attribute__((address_space(1))) unsigned int*)g,
      (__attribute__((address_space(3))) unsigned int*)l, 16, 0, 0);
}

// ---------------------------------------------------------------------------
// Kernel 0: W prep — split-bf16 (hi/lo) of Wq/Wk/Wv, padded to [80][96].
// cols/rows >=72 are ZERO -> B-operand garbage at c>=72 multiplies by 0.
// ---------------------------------------------------------------------------
__global__ __launch_bounds__(256) void wprep_kernel(
    const float* __restrict__ Wq, const float* __restrict__ Wk,
    const float* __restrict__ Wv,
    unsigned short* __restrict__ WH, unsigned short* __restrict__ WL)
{
  int id = blockIdx.x * 256 + threadIdx.x;
  if (id >= 3 * 80 * 96) return;
  int mat = id / (80 * 96);
  int rem = id % (80 * 96);
  int d = rem / 96, c = rem % 96;
  const float* W = (mat == 0) ? Wq : (mat == 1) ? Wk : Wv;
  float v = (d < 72 && c < 72) ? W[d * 72 + c] : 0.f;
  unsigned short hi = f2bf(v);
  WH[id] = hi;
  WL[id] = f2bf(v - bf2f(hi));
}

// ---------------------------------------------------------------------------
// Kernel 1 (v3): QKV projection — unchanged (isolate flash delta).
// ---------------------------------------------------------------------------
#define XTS 104   // obuf row stride (ushorts), 208 B
#define QS  4     // strips per block

static __device__ __forceinline__ void stage_x(const float* __restrict__ x,
    float* lbuf, int b, int n0, int w, int lane) {
  // 6 chunks of 1024B = 96 tile rows x 64B; 2 chunks per wave.
#pragma unroll
  for (int kk = 0; kk < 2; ++kk) {
    const int ch = w * 2 + kk;
    const int r = ch * 16 + (lane >> 2);    // tile row (= padded channel) 0..95
    const int c = (r < 72) ? r : 71;        // clamp: W cols >=72 are zero
    const float* src = x + ((size_t)b * CIN + c) * NPIX + n0 + (lane & 3) * 4;
    load_lds16(src, lbuf + ch * 256);
  }
}

__global__ __launch_bounds__(192, 1) void qkv_kernel(
    const float* __restrict__ x,
    const unsigned short* __restrict__ WH, const unsigned short* __restrict__ WL,
    const float* __restrict__ bq, const float* __restrict__ bk,
    const float* __restrict__ bv,
    unsigned short* __restrict__ QH, unsigned short* __restrict__ KH,
    unsigned short* __restrict__ VG)
{
  __shared__ __align__(16) float ls_x[2][6 * 256];            // 2 x 6144 B
  __shared__ __align__(16) unsigned short obuf[2][16 * XTS];  // Q,K wave slices

  const int t    = threadIdx.x;
  const int w    = t >> 6;           // 0=Q, 1=K, 2=V
  const int lane = t & 63;
  const int quad = lane >> 4;
  const int l15  = lane & 15;
  const int bid  = blockIdx.x;
  const int b    = bid / 144;
  const int g0   = bid % 144;
  const int nbase = g0 * 64;

  // ---- W fragments resident in registers (reused across QS strips) ----
  const unsigned short* wh = WH + w * 80 * 96;
  const unsigned short* wl = WL + w * 80 * 96;
  bf16x8 WAh[5][3], WAl[5][3];
#pragma unroll
  for (int dm = 0; dm < 5; ++dm)
#pragma unroll
    for (int ks = 0; ks < 3; ++ks) {
      WAh[dm][ks] = *(const bf16x8*)(wh + (dm * 16 + l15) * 96 + ks * 32 + quad * 8);
      WAl[dm][ks] = *(const bf16x8*)(wl + (dm * 16 + l15) * 96 + ks * 32 + quad * 8);
    }
  const float* bias = (w == 0) ? bq : (w == 1) ? bk : bv;
  float bs[5][4];
#pragma unroll
  for (int dm = 0; dm < 5; ++dm)
#pragma unroll
    for (int r = 0; r < 4; ++r) {
      int d = dm * 16 + quad * 4 + r;
      bs[dm][r] = (d < 72) ? bias[d] : 0.f;
    }

  stage_x(x, ls_x[0], b, nbase, w, lane);
  __syncthreads();   // drains W loads + strip-0 DMA

  for (int s = 0; s < QS; ++s) {
    const int n0 = nbase + s * 16;
    if (s + 1 < QS) stage_x(x, ls_x[(s + 1) & 1], b, n0 + 16, w, lane);
    const float* lx = ls_x[s & 1];

    // B-operand fragments: column reads (n = l15 = px, k = quad*8+j),
    // split-bf16 on the fly.
    bf16x8 xbh[3], xbl[3];
#pragma unroll
    for (int ks = 0; ks < 3; ++ks) {
#pragma unroll
      for (int j = 0; j < 8; ++j) {
        float v = lx[(ks * 32 + quad * 8 + j) * 16 + l15];
        unsigned short hi = f2bf(v);
        ((unsigned short*)&xbh[ks])[j] = hi;
        ((unsigned short*)&xbl[ks])[j] = f2bf(v - bf2f(hi));
      }
    }

    f32x4 acc[5];
#pragma unroll
    for (int dm = 0; dm < 5; ++dm) {
      acc[dm] = (f32x4){0.f, 0.f, 0.f, 0.f};
#pragma unroll
      for (int ks = 0; ks < 3; ++ks) {
        acc[dm] = MFMA_BF16(WAh[dm][ks], xbh[ks], acc[dm]);
        acc[dm] = MFMA_BF16(WAh[dm][ks], xbl[ks], acc[dm]);
        acc[dm] = MFMA_BF16(WAl[dm][ks], xbh[ks], acc[dm]);
      }
    }

    if (w < 2) {
      // Q/K: bias + fp16, transpose via wave-private obuf (lgkmcnt only),
      // coalesced uint4 stores (cols 9..11 = zero pad)
      unsigned short* ob = obuf[w];
#pragma unroll
      for (int dm = 0; dm < 5; ++dm)
#pragma unroll
        for (int r = 0; r < 4; ++r) {
          int d = dm * 16 + quad * 4 + r;
          float v = acc[dm][r] + bs[dm][r];
          ob[l15 * XTS + d] = f2h(v);
        }
      unsigned short* outp = (w == 0) ? QH : KH;
      const size_t obase = ((size_t)b * NPIX + n0) * CP;
      uint4 z; z.x = z.y = z.z = z.w = 0u;
      for (int f = lane; f < 192; f += 64) {
        int row = f / 12, col = f % 12;
        *(uint4*)(outp + obase + (size_t)row * CP + col * 8) =
            (col < 10) ? *(const uint4*)(ob + row * XTS + col * 8) : z;
      }
    } else {
      // V: bias + bf16, store [c][n] direct; rows 72..79: ones-row + zeros
#pragma unroll
      for (int dm = 0; dm < 5; ++dm)
#pragma unroll
        for (int r = 0; r < 4; ++r) {
          int d = dm * 16 + quad * 4 + r;
          float v = (d < 72) ? acc[dm][r] + bs[dm][r] : (d == 72 ? 1.0f : 0.f);
          VG[((size_t)b * 80 + d) * NPIX + n0 + l15] = f2bf(v);
        }
    }
    __syncthreads();  // LDS-x reads done + next-strip DMA drained
  }
}

// ---------------------------------------------------------------------------
// Kernel 2 (v5): fused flash attention + pooling — occupancy + P-in-register.
// R3 post-mortem: 3 structural LDS/sync variants all 73-76us at MfmaUtil 34%,
// Occ 26% -> latency-chain-bound at 3 blocks/CU (grid-capped) with a >50%-
// duty LDS pipe. This version attacks that regime:
//  * P redistribution IN REGISTERS: {R0,R2}=permlane16_swap(permlane32_swap(
//    Ax,Bx)), {R1,R3} on .y — bit-identical to the old LDS write/read mapping
//    (writer qq=tjh*2+(quad>>1), dword-pair=quad&1  <=>  frag=[x(lo),y(lo),
//    x(hi),y(hi)] from src quads 2(Q&1),2(Q&1)+1 of tj=js*2+(Q>>1)).
//    Deletes 18 LDS ops + the serial write->wait->read RAW, and the 12KB ps.
//  * SPLITS 8->16: grid 1536 (6 blocks/CU available); LDS 22.5KB (7 fit);
//    launch_bounds(256,4) caps VGPR at 128 (no spill risk); occupancy now
//    VGPR/grid-bound at 4-6 blocks/CU = 16-24 waves (was 12).
//  * simple v3 2-barrier loop (best measured); inter-block overlap hides
//    the DMA drains (m114) — no explicit pipelining.
// ---------------------------------------------------------------------------
#define KCH 12    // K chunks per tile: (tj,ks) = 4x3
#define VCH 10    // V chunks per tile: (nt,js) = 5x2

__global__ __launch_bounds__(256, 4) void flash_kernel(
    const float* __restrict__ x,
    const unsigned short* __restrict__ QH, const unsigned short* __restrict__ KH,
    const unsigned short* __restrict__ VG,
    float* __restrict__ NUM, float* __restrict__ LPART)
{
  __shared__ __align__(16) unsigned short ls_kh[KCH * 512];  // 12,288 B
  __shared__ __align__(16) unsigned short ls_vs[VCH * 512];  // 10,240 B

  const int t    = threadIdx.x;
  const int w    = t >> 6;
  const int lane = t & 63;
  const int quad = lane >> 4;
  const int l15  = lane & 15;

  const int bid  = blockIdx.x;
  const int sp   = bid & 15;         // split; sp&7 == XCD (round-robin)
  const int slot = bid >> 4;         // 0..95
  const int b    = slot / 48;
  const int it   = slot % 48;
  const int i0w  = it * 192 + w * 48;

  // Q fragments (B-operand of S^T scores: n=l15=i, k=quad*8+c)
  f16x8 qh[3][3];
#pragma unroll
  for (int mi = 0; mi < 3; ++mi)
#pragma unroll
    for (int ks = 0; ks < 3; ++ks) {
      size_t off = ((size_t)b * NPIX + i0w + mi * 16 + l15) * CP + ks * 32 + quad * 8;
      qh[mi][ks] = *(const f16x8*)(QH + off);
    }

  f32x4 oacc[3][5];   // O^T[c][i]: c = nt*16+quad*4+r, i = mi*16+l15
#pragma unroll
  for (int mi = 0; mi < 3; ++mi)
#pragma unroll
    for (int nt = 0; nt < 5; ++nt) oacc[mi][nt] = (f32x4){0.f, 0.f, 0.f, 0.f};

  const unsigned short* kpg = KH + ((size_t)b * NPIX + sp * JCHUNK) * CP;
  const unsigned short* vpg = VG + (size_t)b * 80 * NPIX + sp * JCHUNK;

  // per-lane gather source offsets (jt-invariant): this wave's chunks c=w+4k.
  // K chunk c=(tj,ks): src = (tj*16 + l&15)*CP + ks*32 + (l>>4)*8
  // V chunk c=(nt,js): src = (nt*16 + l&15)*NPIX + js*32 + (l>>4)*8
  int koff[3], voff[3];
#pragma unroll
  for (int k = 0; k < 3; ++k) {
    int c = w + 4 * k;
    koff[k] = ((c / 3) * 16 + l15) * CP + (c % 3) * 32 + quad * 8;
    int cv = (c < VCH) ? c : 0;
    voff[k] = ((cv >> 1) * 16 + l15) * NPIX + (cv & 1) * 32 + quad * 8;
  }

  for (int jt = 0; jt < JTILES; ++jt, kpg += 64 * CP, vpg += 64) {
    // ---- K tile: 12 fragment-order chunks via DMA (3 per wave) ----
#pragma unroll
    for (int k = 0; k < 3; ++k)
      load_lds16(kpg + koff[k], ls_kh + (w + 4 * k) * 512);
    // ---- V tile: 10 fragment-order chunks via DMA (2-3 per wave) ----
#pragma unroll
    for (int k = 0; k < 3; ++k)
      if (w + 4 * k < VCH)   // wave-uniform guard
        load_lds16(vpg + voff[k], ls_vs + (w + 4 * k) * 512);
    __syncthreads();   // drains vmcnt (all DMA) before LDS reads

#pragma unroll
    for (int js = 0; js < 2; ++js) {
      // ---- S^T for tj = js*2 (->pkA), js*2+1 (->pkB) ----
      uint2 pkA[3], pkB[3];
#pragma unroll
      for (int tjh = 0; tjh < 2; ++tjh) {
        const int tj = js * 2 + tjh;
        f16x8 fkh[3];
#pragma unroll
        for (int ks = 0; ks < 3; ++ks)
          fkh[ks] = *(const f16x8*)(ls_kh + (tj * 3 + ks) * 512 + lane * 8);
#pragma unroll
        for (int mi = 0; mi < 3; ++mi) {
          f32x4 s = (f32x4){0.f, 0.f, 0.f, 0.f};
          s = MFMA_F16(fkh[0], qh[mi][0], s);   // A=K (m=j), B=Q (n=i)
          s = MFMA_F16(fkh[1], qh[mi][1], s);
          s = MFMA_F16(fkh[2], qh[mi][2], s);
          float p0 = __builtin_amdgcn_exp2f(__builtin_fmaf(s[0], L2E, -EXPB));
          float p1 = __builtin_amdgcn_exp2f(__builtin_fmaf(s[1], L2E, -EXPB));
          float p2 = __builtin_amdgcn_exp2f(__builtin_fmaf(s[2], L2E, -EXPB));
          float p3 = __builtin_amdgcn_exp2f(__builtin_fmaf(s[3], L2E, -EXPB));
          uint2 pk;
          pk.x = pack_bf_trunc(p0, p1);
          pk.y = pack_bf_trunc(p2, p3);
          if (tjh == 0) pkA[mi] = pk; else pkB[mi] = pk;
        }
      }

      // ---- P redistribution in-register (replaces LDS round trip) ----
      // lane holds P[j=tj*16+quad*4+r][i]; PV B-frag lane (Q,l15) needs
      // dwords [x(srcq 2(Q&1)), y(same), x(srcq+1), y(srcq+1)] of
      // tj=js*2+(Q>>1). permlane32_swap: vdst.hi <-> vsrc.lo;
      // permlane16_swap: vdst odd 16-rows <-> vsrc even 16-rows.
      bf16x8 pf[3];
#pragma unroll
      for (int mi = 0; mi < 3; ++mi) {
        unsigned x0 = pkA[mi].x, x1 = pkB[mi].x;
        asm("v_permlane32_swap_b32 %0, %1" : "+v"(x0), "+v"(x1));
        asm("v_permlane16_swap_b32 %0, %1" : "+v"(x0), "+v"(x1));
        // x0 = [a0,a2,b0,b2] = R0; x1 = [a1,a3,b1,b3] = R2
        unsigned y0 = pkA[mi].y, y1 = pkB[mi].y;
        asm("v_permlane32_swap_b32 %0, %1" : "+v"(y0), "+v"(y1));
        asm("v_permlane16_swap_b32 %0, %1" : "+v"(y0), "+v"(y1));
        uint4 fr;
        fr.x = x0; fr.y = y0; fr.z = x1; fr.w = y1;
        pf[mi] = *(const bf16x8*)&fr;
      }

      // ---- PV half: A = V (m=c incl. ones-row 72), B = P (regs) ----
#pragma unroll
      for (int nt = 0; nt < 5; ++nt) {
        bf16x8 vf = *(const bf16x8*)(ls_vs + (nt * 2 + js) * 512 + lane * 8);
#pragma unroll
        for (int mi = 0; mi < 3; ++mi)
          oacc[mi][nt] = MFMA_BF16(vf, pf[mi], oacc[mi][nt]);
      }
    }
    __syncthreads();   // all K/V LDS reads done before next staging
  }

  // ---- epilogue: L from ones-row; fused factor-4 pooling -> NUM fp32 ----
  const size_t sb = (size_t)(sp * 2 + b);
#pragma unroll
  for (int mi = 0; mi < 3; ++mi) {
    const int i = i0w + mi * 16 + l15;
    if (quad == 2)   // c = 72: the ones-row -> L
      LPART[sb * NPIX + i] = oacc[mi][4][0];
#pragma unroll
    for (int nt = 0; nt < 5; ++nt) {
      int c0 = nt * 16 + quad * 4;
      if (c0 < 72) {
        float num = 0.f;
#pragma unroll
        for (int r = 0; r < 4; ++r)
          num = __builtin_fmaf(x[((size_t)b * CIN + c0 + r) * NPIX + i],
                               oacc[mi][nt][r], num);
        NUM[(sb * 18 + (c0 >> 2)) * NPIX + i] = num;   // g = nt*4+quad
      }
    }
  }
}

// ---------------------------------------------------------------------------
// Kernel 3: combine splits: out = (sum_s NUM_s) / (sum_s L_s). Trivial.
// ---------------------------------------------------------------------------
__global__ __launch_bounds__(256) void combine_pool_kernel(
    const float* __restrict__ NUM, const float* __restrict__ LPART,
    float* __restrict__ out)
{
  int id = blockIdx.x * 256 + threadIdx.x;
  if (id >= 2 * 18 * (NPIX / 4)) return;
  int n = (id % (NPIX / 4)) * 4;
  int rest = id / (NPIX / 4);       // = b*18 + g
  int g = rest % 18, b = rest / 18;

  float4 A = make_float4(0.f, 0.f, 0.f, 0.f);
  float4 L = make_float4(0.f, 0.f, 0.f, 0.f);
#pragma unroll
  for (int s = 0; s < SPLITS; ++s) {
    size_t sb = (size_t)(s * 2 + b);
    float4 a = *(const float4*)(NUM + (sb * 18 + g) * NPIX + n);
    float4 l = *(const float4*)(LPART + sb * NPIX + n);
    A.x += a.x; A.y += a.y; A.z += a.z; A.w += a.w;
    L.x += l.x; L.y += l.y; L.z += l.z; L.w += l.w;
  }
  float4 r;
  r.x = A.x / L.x; r.y = A.y / L.y; r.z = A.z / L.z; r.w = A.w / L.w;
  *(float4*)(out + (size_t)id * 4) = r;
}

// ---------------------------------------------------------------------------
extern "C" void kernel_launch(void* const* d_in, const int* in_sizes, int n_in,
                              void* d_out, int out_size, void* d_ws, size_t ws_size,
                              hipStream_t stream) {
  const float* x  = (const float*)d_in[0];
  const float* Wq = (const float*)d_in[1];
  const float* bq = (const float*)d_in[2];
  const float* Wk = (const float*)d_in[3];
  const float* bk = (const float*)d_in[4];
  const float* Wv = (const float*)d_in[5];
  const float* bv = (const float*)d_in[6];
  float* out = (float*)d_out;

  char* p = (char*)d_ws;
  const size_t szQK = (size_t)2 * NPIX * CP * 2;
  unsigned short* QH = (unsigned short*)p; p += szQK;
  unsigned short* KH = (unsigned short*)p; p += szQK;
  unsigned short* VG = (unsigned short*)p; p += (size_t)2 * 80 * NPIX * 2;
  unsigned short* WH = (unsigned short*)p; p += (size_t)3 * 80 * 96 * 2;
  unsigned short* WL = (unsigned short*)p; p += (size_t)3 * 80 * 96 * 2;
  float* NUM = (float*)p; p += (size_t)SPLITS * 2 * 18 * NPIX * 4;   // 21.2 MB
  float* LPART = (float*)p; p += (size_t)SPLITS * 2 * NPIX * 4;      // 1.2 MB

  wprep_kernel<<<(3 * 80 * 96 + 255) / 256, 256, 0, stream>>>(Wq, Wk, Wv, WH, WL);
  qkv_kernel<<<288, 192, 0, stream>>>(x, WH, WL, bq, bk, bv, QH, KH, VG);
  flash_kernel<<<SPLITS * 2 * 48, 256, 0, stream>>>(x, QH, KH, VG, NUM, LPART);
  combine_pool_kernel<<<(2 * 18 * (NPIX / 4) + 255) / 256, 256, 0, stream>>>(
      NUM, LPART, out);
}

// Round 5
// 148.306 us; speedup vs baseline: 1.6116x; 1.6116x over previous
//
#include <hip/hip_runtime.h>

#define NPIX 9216
#define CIN 72
#define CP 96
#define SPLITS 8
#define JCHUNK (NPIX / SPLITS)   // 1152
#define JTILES (JCHUNK / 64)     // 18
// p = exp2(s*log2e - 32*log2e)  (fixed softmax shift 32; safe to s<120)
#define L2E   1.44269504088896f
#define EXPB  46.1662413084468f

typedef __attribute__((ext_vector_type(8))) short bf16x8;
typedef __attribute__((ext_vector_type(8))) _Float16 f16x8;
typedef __attribute__((ext_vector_type(4))) float f32x4;

#define MFMA_BF16(A,B,C) __builtin_amdgcn_mfma_f32_16x16x32_bf16(A,B,C,0,0,0)
#define MFMA_F16(A,B,C)  __builtin_amdgcn_mfma_f32_16x16x32_f16(A,B,C,0,0,0)

static __device__ __forceinline__ unsigned short f2bf(float f) {
  unsigned u = __float_as_uint(f);
  u += 0x7fffu + ((u >> 16) & 1u);
  return (unsigned short)(u >> 16);
}
static __device__ __forceinline__ float bf2f(unsigned short h) {
  return __uint_as_float(((unsigned)h) << 16);
}
static __device__ __forceinline__ unsigned short f2h(float f) {
  _Float16 h = (_Float16)f;
  return *(unsigned short*)&h;
}
// pack trunc-bf16 of (lo,hi) into one dword: [lo.hi16 | hi.hi16]
static __device__ __forceinline__ unsigned pack_bf_trunc(float lo, float hi) {
  return (__float_as_uint(lo) >> 16) | (__float_as_uint(hi) & 0xffff0000u);
}
// async global->LDS DMA, 16B per lane; lds dest = uniform base + lane*16.
// global src is PER-LANE (m173): fragment-order LDS = per-lane gather src.
static __device__ __forceinline__ void load_lds16(const void* g, void* l) {
  __builtin_amdgcn_global_load_lds(
      (const __attribute__((address_space(1))) unsigned int*)g,
      (__attribute__((address_space(3))) unsigned int*)l, 16, 0, 0);
}

// ---------------------------------------------------------------------------
// Kernel 0: W prep — split-bf16 (hi/lo) of Wq/Wk/Wv, padded to [80][96].
// cols/rows >=72 are ZERO -> B-operand garbage at c>=72 multiplies by 0.
// ---------------------------------------------------------------------------
__global__ __launch_bounds__(256) void wprep_kernel(
    const float* __restrict__ Wq, const float* __restrict__ Wk,
    const float* __restrict__ Wv,
    unsigned short* __restrict__ WH, unsigned short* __restrict__ WL)
{
  int id = blockIdx.x * 256 + threadIdx.x;
  if (id >= 3 * 80 * 96) return;
  int mat = id / (80 * 96);
  int rem = id % (80 * 96);
  int d = rem / 96, c = rem % 96;
  const float* W = (mat == 0) ? Wq : (mat == 1) ? Wk : Wv;
  float v = (d < 72 && c < 72) ? W[d * 72 + c] : 0.f;
  unsigned short hi = f2bf(v);
  WH[id] = hi;
  WL[id] = f2bf(v - bf2f(hi));
}

// ---------------------------------------------------------------------------
// Kernel 1 (v3): QKV projection — unchanged (isolate flash delta).
// ---------------------------------------------------------------------------
#define XTS 104   // obuf row stride (ushorts), 208 B
#define QS  4     // strips per block

static __device__ __forceinline__ void stage_x(const float* __restrict__ x,
    float* lbuf, int b, int n0, int w, int lane) {
  // 6 chunks of 1024B = 96 tile rows x 64B; 2 chunks per wave.
#pragma unroll
  for (int kk = 0; kk < 2; ++kk) {
    const int ch = w * 2 + kk;
    const int r = ch * 16 + (lane >> 2);    // tile row (= padded channel) 0..95
    const int c = (r < 72) ? r : 71;        // clamp: W cols >=72 are zero
    const float* src = x + ((size_t)b * CIN + c) * NPIX + n0 + (lane & 3) * 4;
    load_lds16(src, lbuf + ch * 256);
  }
}

__global__ __launch_bounds__(192, 1) void qkv_kernel(
    const float* __restrict__ x,
    const unsigned short* __restrict__ WH, const unsigned short* __restrict__ WL,
    const float* __restrict__ bq, const float* __restrict__ bk,
    const float* __restrict__ bv,
    unsigned short* __restrict__ QH, unsigned short* __restrict__ KH,
    unsigned short* __restrict__ VG)
{
  __shared__ __align__(16) float ls_x[2][6 * 256];            // 2 x 6144 B
  __shared__ __align__(16) unsigned short obuf[2][16 * XTS];  // Q,K wave slices

  const int t    = threadIdx.x;
  const int w    = t >> 6;           // 0=Q, 1=K, 2=V
  const int lane = t & 63;
  const int quad = lane >> 4;
  const int l15  = lane & 15;
  const int bid  = blockIdx.x;
  const int b    = bid / 144;
  const int g0   = bid % 144;
  const int nbase = g0 * 64;

  // ---- W fragments resident in registers (reused across QS strips) ----
  const unsigned short* wh = WH + w * 80 * 96;
  const unsigned short* wl = WL + w * 80 * 96;
  bf16x8 WAh[5][3], WAl[5][3];
#pragma unroll
  for (int dm = 0; dm < 5; ++dm)
#pragma unroll
    for (int ks = 0; ks < 3; ++ks) {
      WAh[dm][ks] = *(const bf16x8*)(wh + (dm * 16 + l15) * 96 + ks * 32 + quad * 8);
      WAl[dm][ks] = *(const bf16x8*)(wl + (dm * 16 + l15) * 96 + ks * 32 + quad * 8);
    }
  const float* bias = (w == 0) ? bq : (w == 1) ? bk : bv;
  float bs[5][4];
#pragma unroll
  for (int dm = 0; dm < 5; ++dm)
#pragma unroll
    for (int r = 0; r < 4; ++r) {
      int d = dm * 16 + quad * 4 + r;
      bs[dm][r] = (d < 72) ? bias[d] : 0.f;
    }

  stage_x(x, ls_x[0], b, nbase, w, lane);
  __syncthreads();   // drains W loads + strip-0 DMA

  for (int s = 0; s < QS; ++s) {
    const int n0 = nbase + s * 16;
    if (s + 1 < QS) stage_x(x, ls_x[(s + 1) & 1], b, n0 + 16, w, lane);
    const float* lx = ls_x[s & 1];

    // B-operand fragments: column reads (n = l15 = px, k = quad*8+j),
    // split-bf16 on the fly.
    bf16x8 xbh[3], xbl[3];
#pragma unroll
    for (int ks = 0; ks < 3; ++ks) {
#pragma unroll
      for (int j = 0; j < 8; ++j) {
        float v = lx[(ks * 32 + quad * 8 + j) * 16 + l15];
        unsigned short hi = f2bf(v);
        ((unsigned short*)&xbh[ks])[j] = hi;
        ((unsigned short*)&xbl[ks])[j] = f2bf(v - bf2f(hi));
      }
    }

    f32x4 acc[5];
#pragma unroll
    for (int dm = 0; dm < 5; ++dm) {
      acc[dm] = (f32x4){0.f, 0.f, 0.f, 0.f};
#pragma unroll
      for (int ks = 0; ks < 3; ++ks) {
        acc[dm] = MFMA_BF16(WAh[dm][ks], xbh[ks], acc[dm]);
        acc[dm] = MFMA_BF16(WAh[dm][ks], xbl[ks], acc[dm]);
        acc[dm] = MFMA_BF16(WAl[dm][ks], xbh[ks], acc[dm]);
      }
    }

    if (w < 2) {
      // Q/K: bias + fp16, transpose via wave-private obuf (lgkmcnt only),
      // coalesced uint4 stores (cols 9..11 = zero pad)
      unsigned short* ob = obuf[w];
#pragma unroll
      for (int dm = 0; dm < 5; ++dm)
#pragma unroll
        for (int r = 0; r < 4; ++r) {
          int d = dm * 16 + quad * 4 + r;
          float v = acc[dm][r] + bs[dm][r];
          ob[l15 * XTS + d] = f2h(v);
        }
      unsigned short* outp = (w == 0) ? QH : KH;
      const size_t obase = ((size_t)b * NPIX + n0) * CP;
      uint4 z; z.x = z.y = z.z = z.w = 0u;
      for (int f = lane; f < 192; f += 64) {
        int row = f / 12, col = f % 12;
        *(uint4*)(outp + obase + (size_t)row * CP + col * 8) =
            (col < 10) ? *(const uint4*)(ob + row * XTS + col * 8) : z;
      }
    } else {
      // V: bias + bf16, store [c][n] direct; rows 72..79: ones-row + zeros
#pragma unroll
      for (int dm = 0; dm < 5; ++dm)
#pragma unroll
        for (int r = 0; r < 4; ++r) {
          int d = dm * 16 + quad * 4 + r;
          float v = (d < 72) ? acc[dm][r] + bs[dm][r] : (d == 72 ? 1.0f : 0.f);
          VG[((size_t)b * 80 + d) * NPIX + n0 + l15] = f2bf(v);
        }
    }
    __syncthreads();  // LDS-x reads done + next-strip DMA drained
  }
}

// ---------------------------------------------------------------------------
// Kernel 2 (v6): fused flash attention + pooling.
// R4 post-mortem: launch_bounds(256,4) forced a 128-reg unified budget on a
// kernel needing ~150 (oacc 60 AGPR + qh 36 + temps) -> massive scratch
// spill (WRITE 178MB for 22MB of data, FETCH 276MB, BW-bound at 2.9TB/s).
// But it VALIDATED the permlane P-redistribution: passed, conflicts = 0.
// v6 = R2's proven structure (SPLITS=8, single-buffered DMA, 2 barriers/jt,
// launch_bounds(256,3) -> no spill at ~84 VGPR + 60 AGPR) with ONE change:
// P stays in registers via permlane swaps instead of the LDS round trip.
//   {R0,R2} = permlane16_swap(permlane32_swap(Ax,Bx)); {R1,R3} same on .y —
// bit-identical to the old write/read mapping (writer qq=tjh*2+(quad>>1),
// dword-pair=quad&1  <=>  frag=[x(lo),y(lo),x(hi),y(hi)] from src quads
// 2(Q&1),2(Q&1)+1 of tj=js*2+(Q>>1)). Deletes 12 ds_write_b64 + 6
// ds_read_b128 per wave-iter AND the serial write->lgkmcnt->read RAW (x2/jt)
// on the latency-critical path. LDS: 12288(K)+10240(V) = 22528 B.
// ---------------------------------------------------------------------------
#define KCH 12    // K chunks per tile: (tj,ks) = 4x3
#define VCH 10    // V chunks per tile: (nt,js) = 5x2

__global__ __launch_bounds__(256, 3) void flash_kernel(
    const float* __restrict__ x,
    const unsigned short* __restrict__ QH, const unsigned short* __restrict__ KH,
    const unsigned short* __restrict__ VG,
    float* __restrict__ NUM, float* __restrict__ LPART)
{
  __shared__ __align__(16) unsigned short ls_kh[KCH * 512];  // 12,288 B
  __shared__ __align__(16) unsigned short ls_vs[VCH * 512];  // 10,240 B

  const int t    = threadIdx.x;
  const int w    = t >> 6;
  const int lane = t & 63;
  const int quad = lane >> 4;
  const int l15  = lane & 15;

  const int bid  = blockIdx.x;
  const int sp   = bid & 7;          // split == XCD id (round-robin dispatch)
  const int slot = bid >> 3;
  const int b    = slot / 48;
  const int it   = slot % 48;
  const int i0w  = it * 192 + w * 48;

  // Q fragments (B-operand of S^T scores: n=l15=i, k=quad*8+c)
  f16x8 qh[3][3];
#pragma unroll
  for (int mi = 0; mi < 3; ++mi)
#pragma unroll
    for (int ks = 0; ks < 3; ++ks) {
      size_t off = ((size_t)b * NPIX + i0w + mi * 16 + l15) * CP + ks * 32 + quad * 8;
      qh[mi][ks] = *(const f16x8*)(QH + off);
    }

  f32x4 oacc[3][5];   // O^T[c][i]: c = nt*16+quad*4+r, i = mi*16+l15
#pragma unroll
  for (int mi = 0; mi < 3; ++mi)
#pragma unroll
    for (int nt = 0; nt < 5; ++nt) oacc[mi][nt] = (f32x4){0.f, 0.f, 0.f, 0.f};

  const unsigned short* kpg = KH + ((size_t)b * NPIX + sp * JCHUNK) * CP;
  const unsigned short* vpg = VG + (size_t)b * 80 * NPIX + sp * JCHUNK;

  // per-lane gather source offsets (jt-invariant): this wave's chunks c=w+4k.
  // K chunk c=(tj,ks): src = (tj*16 + l&15)*CP + ks*32 + (l>>4)*8
  // V chunk c=(nt,js): src = (nt*16 + l&15)*NPIX + js*32 + (l>>4)*8
  int koff[3], voff[3];
#pragma unroll
  for (int k = 0; k < 3; ++k) {
    int c = w + 4 * k;
    koff[k] = ((c / 3) * 16 + l15) * CP + (c % 3) * 32 + quad * 8;
    int cv = (c < VCH) ? c : 0;
    voff[k] = ((cv >> 1) * 16 + l15) * NPIX + (cv & 1) * 32 + quad * 8;
  }

  for (int jt = 0; jt < JTILES; ++jt, kpg += 64 * CP, vpg += 64) {
    // ---- K tile: 12 fragment-order chunks via DMA (3 per wave) ----
#pragma unroll
    for (int k = 0; k < 3; ++k)
      load_lds16(kpg + koff[k], ls_kh + (w + 4 * k) * 512);
    // ---- V tile: 10 fragment-order chunks via DMA (2-3 per wave) ----
#pragma unroll
    for (int k = 0; k < 3; ++k)
      if (w + 4 * k < VCH)   // wave-uniform guard
        load_lds16(vpg + voff[k], ls_vs + (w + 4 * k) * 512);
    __syncthreads();   // drains vmcnt (all DMA) before LDS reads

#pragma unroll
    for (int js = 0; js < 2; ++js) {
      // ---- S^T for tj = js*2 (->pkA), js*2+1 (->pkB) ----
      uint2 pkA[3], pkB[3];
#pragma unroll
      for (int tjh = 0; tjh < 2; ++tjh) {
        const int tj = js * 2 + tjh;
        f16x8 fkh[3];
#pragma unroll
        for (int ks = 0; ks < 3; ++ks)
          fkh[ks] = *(const f16x8*)(ls_kh + (tj * 3 + ks) * 512 + lane * 8);
#pragma unroll
        for (int mi = 0; mi < 3; ++mi) {
          f32x4 s = (f32x4){0.f, 0.f, 0.f, 0.f};
          s = MFMA_F16(fkh[0], qh[mi][0], s);   // A=K (m=j), B=Q (n=i)
          s = MFMA_F16(fkh[1], qh[mi][1], s);
          s = MFMA_F16(fkh[2], qh[mi][2], s);
          float p0 = __builtin_amdgcn_exp2f(__builtin_fmaf(s[0], L2E, -EXPB));
          float p1 = __builtin_amdgcn_exp2f(__builtin_fmaf(s[1], L2E, -EXPB));
          float p2 = __builtin_amdgcn_exp2f(__builtin_fmaf(s[2], L2E, -EXPB));
          float p3 = __builtin_amdgcn_exp2f(__builtin_fmaf(s[3], L2E, -EXPB));
          uint2 pk;
          pk.x = pack_bf_trunc(p0, p1);
          pk.y = pack_bf_trunc(p2, p3);
          if (tjh == 0) pkA[mi] = pk; else pkB[mi] = pk;
        }
      }

      // ---- P redistribution in-register (replaces LDS round trip) ----
      // lane holds P[j=tj*16+quad*4+r][i]; PV B-frag lane (Q,l15) needs
      // dwords [x(srcq 2(Q&1)), y(same), x(srcq+1), y(srcq+1)] of
      // tj=js*2+(Q>>1). permlane32_swap: vdst.hi <-> vsrc.lo;
      // permlane16_swap: vdst odd 16-rows <-> vsrc even 16-rows.
      bf16x8 pf[3];
#pragma unroll
      for (int mi = 0; mi < 3; ++mi) {
        unsigned x0 = pkA[mi].x, x1 = pkB[mi].x;
        asm("v_permlane32_swap_b32 %0, %1" : "+v"(x0), "+v"(x1));
        asm("v_permlane16_swap_b32 %0, %1" : "+v"(x0), "+v"(x1));
        // x0 = [a0,a2,b0,b2] = R0; x1 = [a1,a3,b1,b3] = R2
        unsigned y0 = pkA[mi].y, y1 = pkB[mi].y;
        asm("v_permlane32_swap_b32 %0, %1" : "+v"(y0), "+v"(y1));
        asm("v_permlane16_swap_b32 %0, %1" : "+v"(y0), "+v"(y1));
        uint4 fr;
        fr.x = x0; fr.y = y0; fr.z = x1; fr.w = y1;
        pf[mi] = *(const bf16x8*)&fr;
      }

      // ---- PV half: A = V (m=c incl. ones-row 72), B = P (regs) ----
#pragma unroll
      for (int nt = 0; nt < 5; ++nt) {
        bf16x8 vf = *(const bf16x8*)(ls_vs + (nt * 2 + js) * 512 + lane * 8);
#pragma unroll
        for (int mi = 0; mi < 3; ++mi)
          oacc[mi][nt] = MFMA_BF16(vf, pf[mi], oacc[mi][nt]);
      }
    }
    __syncthreads();   // all K/V LDS reads done before next staging
  }

  // ---- epilogue: L from ones-row; fused factor-4 pooling -> NUM fp32 ----
  const size_t sb = (size_t)(sp * 2 + b);
#pragma unroll
  for (int mi = 0; mi < 3; ++mi) {
    const int i = i0w + mi * 16 + l15;
    if (quad == 2)   // c = 72: the ones-row -> L
      LPART[sb * NPIX + i] = oacc[mi][4][0];
#pragma unroll
    for (int nt = 0; nt < 5; ++nt) {
      int c0 = nt * 16 + quad * 4;
      if (c0 < 72) {
        float num = 0.f;
#pragma unroll
        for (int r = 0; r < 4; ++r)
          num = __builtin_fmaf(x[((size_t)b * CIN + c0 + r) * NPIX + i],
                               oacc[mi][nt][r], num);
        NUM[(sb * 18 + (c0 >> 2)) * NPIX + i] = num;   // g = nt*4+quad
      }
    }
  }
}

// ---------------------------------------------------------------------------
// Kernel 3: combine splits: out = (sum_s NUM_s) / (sum_s L_s). Trivial.
// ---------------------------------------------------------------------------
__global__ __launch_bounds__(256) void combine_pool_kernel(
    const float* __restrict__ NUM, const float* __restrict__ LPART,
    float* __restrict__ out)
{
  int id = blockIdx.x * 256 + threadIdx.x;
  if (id >= 2 * 18 * (NPIX / 4)) return;
  int n = (id % (NPIX / 4)) * 4;
  int rest = id / (NPIX / 4);       // = b*18 + g
  int g = rest % 18, b = rest / 18;

  float4 A = make_float4(0.f, 0.f, 0.f, 0.f);
  float4 L = make_float4(0.f, 0.f, 0.f, 0.f);
#pragma unroll
  for (int s = 0; s < SPLITS; ++s) {
    size_t sb = (size_t)(s * 2 + b);
    float4 a = *(const float4*)(NUM + (sb * 18 + g) * NPIX + n);
    float4 l = *(const float4*)(LPART + sb * NPIX + n);
    A.x += a.x; A.y += a.y; A.z += a.z; A.w += a.w;
    L.x += l.x; L.y += l.y; L.z += l.z; L.w += l.w;
  }
  float4 r;
  r.x = A.x / L.x; r.y = A.y / L.y; r.z = A.z / L.z; r.w = A.w / L.w;
  *(float4*)(out + (size_t)id * 4) = r;
}

// ---------------------------------------------------------------------------
extern "C" void kernel_launch(void* const* d_in, const int* in_sizes, int n_in,
                              void* d_out, int out_size, void* d_ws, size_t ws_size,
                              hipStream_t stream) {
  const float* x  = (const float*)d_in[0];
  const float* Wq = (const float*)d_in[1];
  const float* bq = (const float*)d_in[2];
  const float* Wk = (const float*)d_in[3];
  const float* bk = (const float*)d_in[4];
  const float* Wv = (const float*)d_in[5];
  const float* bv = (const float*)d_in[6];
  float* out = (float*)d_out;

  char* p = (char*)d_ws;
  const size_t szQK = (size_t)2 * NPIX * CP * 2;
  unsigned short* QH = (unsigned short*)p; p += szQK;
  unsigned short* KH = (unsigned short*)p; p += szQK;
  unsigned short* VG = (unsigned short*)p; p += (size_t)2 * 80 * NPIX * 2;
  unsigned short* WH = (unsigned short*)p; p += (size_t)3 * 80 * 96 * 2;
  unsigned short* WL = (unsigned short*)p; p += (size_t)3 * 80 * 96 * 2;
  float* NUM = (float*)p; p += (size_t)SPLITS * 2 * 18 * NPIX * 4;   // 10.6 MB
  float* LPART = (float*)p; p += (size_t)SPLITS * 2 * NPIX * 4;      // 0.6 MB

  wprep_kernel<<<(3 * 80 * 96 + 255) / 256, 256, 0, stream>>>(Wq, Wk, Wv, WH, WL);
  qkv_kernel<<<288, 192, 0, stream>>>(x, WH, WL, bq, bk, bv, QH, KH, VG);
  flash_kernel<<<SPLITS * 2 * 48, 256, 0, stream>>>(x, QH, KH, VG, NUM, LPART);
  combine_pool_kernel<<<(2 * 18 * (NPIX / 4) + 255) / 256, 256, 0, stream>>>(
      NUM, LPART, out);
}